// Round 2
// baseline (904.399 us; speedup 1.0000x reference)
//
#include <hip/hip_runtime.h>

// Simple_TensorProduct: (256x0e + 256x1o) x (1x0e + 1x1o) -> 256x0e + 256x1o
// uvu weights, 5 paths. Memory-bound: 537 MB in + 537 MB out per call.
//
// Per z, per u:
//   o0[u]   = C0*( w0[u]*x0[u]*y0 + S3*w1[u]*dot(x1[u], y1) )
//   o1[u,k] = S3*w2[u]*x0[u]*y1[k] + S3*w3[u]*y0*x1[u,k] + C6*w4[u]*cross(x1[u],y1)[k]
//
// Structure (v2b): persistent grid-stride kernel, 2048 blocks x 256 threads.
//  - thread owns u-quad u = 4*lane..4*lane+3 (lane = tid&63) -> every x/out access
//    is a 16B dwordx4 (x0: 1 float4; x1: 3 float4s covering 12 consecutive floats).
//  - 4 rows per block-iteration (tid>>6 selects row), so all 256 lanes stay hot.
//  - weights (5 paths x 4 channels = 20 floats) hoisted into registers ONCE per
//    thread instead of once per row (they are invariant across z).
//  - nontemporal loads/stores: x/out are streamed exactly once (>> 32 MB L2).

namespace {

constexpr int MUL  = 256;
constexpr int ROWF = MUL * 4;  // 1024 floats per row
constexpr int ROW4 = MUL;      // 256 float4s per row

constexpr float C0 = 0.70710678118654752f;  // sqrt(1/2)
constexpr float S3 = 0.57735026918962576f;  // 1/sqrt(3)
constexpr float C6 = 0.40824829046386302f;  // 1/sqrt(6)

using f4 = __attribute__((ext_vector_type(4))) float;

struct TPOut { float o0, ox, oy, oz; };

__device__ __forceinline__ TPOut tp1(
    float x0, float x1x, float x1y, float x1z,
    float y0, float y1x, float y1y, float y1z,
    float w0, float w1, float w2, float w3, float w4)
{
    const float dot = x1x * y1x + x1y * y1y + x1z * y1z;
    const float cx  = x1y * y1z - x1z * y1y;
    const float cy  = x1z * y1x - x1x * y1z;
    const float cz  = x1x * y1y - x1y * y1x;
    TPOut r;
    r.o0 = C0 * (w0 * x0 * y0 + S3 * w1 * dot);
    const float a = S3 * w2 * x0;   // * y1[k]
    const float b = S3 * w3 * y0;   // * x1[k]
    const float c = C6 * w4;        // * cross[k]
    r.ox = a * y1x + b * x1x + c * cx;
    r.oy = a * y1y + b * x1y + c * cy;
    r.oz = a * y1z + b * x1z + c * cz;
    return r;
}

__global__ __launch_bounds__(256) void tp_kernel(
    const f4* __restrict__ x4,
    const f4* __restrict__ y4,
    const f4* __restrict__ wq,
    f4* __restrict__ out4,
    int nrows)
{
    const int lane = threadIdx.x & 63;   // u-quad index: u = 4*lane .. 4*lane+3
    const int rsub = threadIdx.x >> 6;   // row-within-group: 0..3

    // weights for this thread's 4 channels, all 5 paths — loop-invariant
    const f4 w0  = wq[       lane];
    const f4 w1  = wq[ 64 +  lane];
    const f4 w2  = wq[128 +  lane];
    const f4 w3  = wq[192 +  lane];
    const f4 w4v = wq[256 +  lane];

    const int zstride = gridDim.x * 4;
    for (int z = blockIdx.x * 4 + rsub; z < nrows; z += zstride) {
        const f4 yv = y4[z];               // 16B broadcast within the 64-lane group
        const float y0  = yv.x;
        const float y1x = yv.y, y1y = yv.z, y1z = yv.w;

        const f4* xr   = x4   + (size_t)z * ROW4;
        f4*       orow = out4 + (size_t)z * ROW4;

        // x0: 4 consecutive scalars; x1: 12 consecutive floats = 3 float4s
        const f4 x0q = __builtin_nontemporal_load(xr + lane);
        const f4 xa  = __builtin_nontemporal_load(xr + 64 + 3 * lane);
        const f4 xb  = __builtin_nontemporal_load(xr + 64 + 3 * lane + 1);
        const f4 xc  = __builtin_nontemporal_load(xr + 64 + 3 * lane + 2);

        // u0: x1 = (xa.x, xa.y, xa.z)
        const TPOut r0 = tp1(x0q.x, xa.x, xa.y, xa.z, y0, y1x, y1y, y1z,
                             w0.x, w1.x, w2.x, w3.x, w4v.x);
        // u1: x1 = (xa.w, xb.x, xb.y)
        const TPOut r1 = tp1(x0q.y, xa.w, xb.x, xb.y, y0, y1x, y1y, y1z,
                             w0.y, w1.y, w2.y, w3.y, w4v.y);
        // u2: x1 = (xb.z, xb.w, xc.x)
        const TPOut r2 = tp1(x0q.z, xb.z, xb.w, xc.x, y0, y1x, y1y, y1z,
                             w0.z, w1.z, w2.z, w3.z, w4v.z);
        // u3: x1 = (xc.y, xc.z, xc.w)
        const TPOut r3 = tp1(x0q.w, xc.y, xc.z, xc.w, y0, y1x, y1y, y1z,
                             w0.w, w1.w, w2.w, w3.w, w4v.w);

        f4 o0q, oa, ob, oc;
        o0q.x = r0.o0; o0q.y = r1.o0; o0q.z = r2.o0; o0q.w = r3.o0;
        oa.x = r0.ox;  oa.y = r0.oy;  oa.z = r0.oz;  oa.w = r1.ox;
        ob.x = r1.oy;  ob.y = r1.oz;  ob.z = r2.ox;  ob.w = r2.oy;
        oc.x = r2.oz;  oc.y = r3.ox;  oc.z = r3.oy;  oc.w = r3.oz;

        __builtin_nontemporal_store(o0q, orow + lane);
        __builtin_nontemporal_store(oa,  orow + 64 + 3 * lane);
        __builtin_nontemporal_store(ob,  orow + 64 + 3 * lane + 1);
        __builtin_nontemporal_store(oc,  orow + 64 + 3 * lane + 2);
    }
}

}  // namespace

extern "C" void kernel_launch(void* const* d_in, const int* in_sizes, int n_in,
                              void* d_out, int out_size, void* d_ws, size_t ws_size,
                              hipStream_t stream) {
    const f4* x = (const f4*)d_in[0];   // (B, 1024) floats
    const f4* y = (const f4*)d_in[1];   // (B, 4) floats
    const f4* w = (const f4*)d_in[2];   // (1280,) floats
    f4* out = (f4*)d_out;               // (B, 1024) floats

    const int B = in_sizes[0] / ROWF;   // 131072

    int blocks = 2048;                  // 256 CUs x 8 blocks, grid-stride the rest
    if (blocks * 4 > B) blocks = (B + 3) / 4;
    tp_kernel<<<blocks, 256, 0, stream>>>(x, y, w, out, B);
}